// Round 2
// baseline (202.766 us; speedup 1.0000x reference)
//
#include <hip/hip_runtime.h>
#include <hip/hip_bf16.h>

#define B 8
#define N 1024
#define E 10
#define TR 16      // rows per k_iter block
#define JC 128     // j-chunk
#define LDE 20     // padded row stride (floats) for base/emb buffers

// ---------------------------------------------------------------------------
// K1: fused column-sum + base + emb0.
//   relu(w*c) summed over rows == c>0 ? c*sum(max(w,0)) : (-c)*sum(max(-w,0))
//   Grid: 8 b x 32 col-groups(32 cols) = 256 blocks. One HBM pass over W.
//   Also zeroes qsum (block 0).
// ---------------------------------------------------------------------------
__global__ __launch_bounds__(256) void k_base(const float* __restrict__ W,
                                              const float* __restrict__ features,
                                              const float* __restrict__ w_sel,
                                              const float* __restrict__ w_nbw,
                                              const float* __restrict__ w_ew,
                                              float* __restrict__ basePad,
                                              float* __restrict__ emb0,
                                              float* __restrict__ qsum) {
    __shared__ float red[2][8][32];
    __shared__ float scol[2][32];
    __shared__ float wS[120];   // [0..9]=w_sel, [10..19]=w_ew, [20..119]=w_nbw
    int bx = blockIdx.x;
    int b = bx >> 5, c0 = (bx & 31) * 32;
    int tid = threadIdx.x;
    if (tid < 10) wS[tid] = w_sel[tid];
    else if (tid < 20) wS[tid] = w_ew[tid - 10];
    else if (tid < 120) wS[tid] = w_nbw[tid - 20];
    if (bx == 0 && tid < 8) qsum[tid] = 0.f;

    int col = tid & 31, g = tid >> 5;    // 8 row-groups x 128 rows
    const float* wp = W + ((size_t)(b * N) + g * 128) * N + c0 + col;
    float sp = 0.f, sn = 0.f;
#pragma unroll 8
    for (int i = 0; i < 128; ++i) {
        float w = wp[(size_t)i * N];
        sp += fmaxf(w, 0.f);
        sn += fmaxf(-w, 0.f);
    }
    red[0][g][col] = sp;
    red[1][g][col] = sn;
    __syncthreads();
    if (tid < 64) {
        int which = tid >> 5, cc = tid & 31;
        float s = 0.f;
#pragma unroll
        for (int gg = 0; gg < 8; ++gg) s += red[which][gg][cc];
        scol[which][cc] = s;
    }
    __syncthreads();
    // 320 outputs (32 cols x 10 f)
    for (int q = tid; q < 320; q += 256) {
        int cc = q / E, f = q % E;
        float spc = scol[0][cc], snc = scol[1][cc];
        float feat = features[(b << 10) + c0 + cc];
        float acc = feat * wS[f];
#pragma unroll
        for (int e = 0; e < E; ++e) {
            float c = wS[10 + e];
            float se = (c > 0.f) ? c * spc : (-c) * snc;
            acc += wS[20 + f * E + e] * se;
        }
        size_t gi = (size_t)((b << 10) + c0 + cc);
        basePad[gi * LDE + f] = acc;
        emb0[gi * LDE + f] = fmaxf(acc, 0.f);
    }
}

// ---------------------------------------------------------------------------
// K2: one embedding iteration. v[i,e]=sum_j A[i,j]*em[j,e]; out=relu(base+v@Wp^T)
//   Grid 512 = 8 b x 64 tiles(16 rows); block 256 (4 waves) -> 2 blocks/CU.
//   Lane owns 4 rows {m,m+4,m+8,m+12} (m=tid&3); substream s=tid>>2 owns
//   j in {s, s+64} per 128-j chunk -> each ein LDS row read feeds 40 FMAs.
//   A staged untransposed (row stride 132: 2-way max conflicts);
//   Em staged by straight float4 copy (row stride 20: 2-way max).
//   FINAL: writes compact emb to d_out + atomicAdd q-partial into qsum.
// ---------------------------------------------------------------------------
template <int FINAL>
__global__ __launch_bounds__(256) void k_iter(const float* __restrict__ A,
                                              const float* __restrict__ ein,
                                              const float* __restrict__ basePad,
                                              const float* __restrict__ Wp,
                                              const float* __restrict__ w_reduc,
                                              const float* __restrict__ w_all,
                                              float* __restrict__ eout,
                                              float* __restrict__ qsum) {
    __shared__ float Ar[TR][JC + 4];     // 16 x 132 = 8.4 KB
    __shared__ float Em[JC][LDE];        // 128 x 20 = 10 KB
    __shared__ float vredW[4][4][40];    // 2.6 KB
    __shared__ float WpS[E * E];
    __shared__ float wred[4];

    int bx = blockIdx.x;
    int b = bx >> 6, tile = bx & 63;
    int i0 = tile * TR;
    int tid = threadIdx.x;
    if (tid < E * E) WpS[tid] = Wp[tid];

    int s = tid >> 2;      // substream 0..63
    int m = tid & 3;       // row residue

    float acc[4][E];
#pragma unroll
    for (int rr = 0; rr < 4; ++rr)
#pragma unroll
        for (int e = 0; e < E; ++e) acc[rr][e] = 0.f;

    const float* Ab = A + ((size_t)(b * N + i0)) * N;
    const float* Eb = ein + (size_t)b * N * LDE;

    for (int c = 0; c < N / JC; ++c) {
        __syncthreads();   // previous chunk's reads done before overwrite
        // stage A tile: 16 rows x 128 cols = 512 float4
#pragma unroll
        for (int k = 0; k < 2; ++k) {
            int uu = tid + k * 256;
            int rr = uu >> 5, cu = uu & 31;
            float4 v = *(const float4*)(Ab + (size_t)rr * N + c * JC + cu * 4);
            *(float4*)(&Ar[rr][cu * 4]) = v;
        }
        // stage Em chunk: 128 rows x 20 floats contiguous = 640 float4
        {
            const float4* src = (const float4*)(Eb + (size_t)c * JC * LDE);
            float4* dst = (float4*)(&Em[0][0]);
            for (int u = tid; u < JC * LDE / 4; u += 256) dst[u] = src[u];
        }
        __syncthreads();
#pragma unroll
        for (int jj = 0; jj < 2; ++jj) {
            int j = s + 64 * jj;
            const float* er = &Em[j][0];
            float4 e0 = *(const float4*)(er);
            float4 e1 = *(const float4*)(er + 4);
            float2 e2 = *(const float2*)(er + 8);
            float a0 = Ar[m][j];
            float a1 = Ar[m + 4][j];
            float a2 = Ar[m + 8][j];
            float a3 = Ar[m + 12][j];
            acc[0][0] += a0 * e0.x; acc[0][1] += a0 * e0.y; acc[0][2] += a0 * e0.z; acc[0][3] += a0 * e0.w;
            acc[0][4] += a0 * e1.x; acc[0][5] += a0 * e1.y; acc[0][6] += a0 * e1.z; acc[0][7] += a0 * e1.w;
            acc[0][8] += a0 * e2.x; acc[0][9] += a0 * e2.y;
            acc[1][0] += a1 * e0.x; acc[1][1] += a1 * e0.y; acc[1][2] += a1 * e0.z; acc[1][3] += a1 * e0.w;
            acc[1][4] += a1 * e1.x; acc[1][5] += a1 * e1.y; acc[1][6] += a1 * e1.z; acc[1][7] += a1 * e1.w;
            acc[1][8] += a1 * e2.x; acc[1][9] += a1 * e2.y;
            acc[2][0] += a2 * e0.x; acc[2][1] += a2 * e0.y; acc[2][2] += a2 * e0.z; acc[2][3] += a2 * e0.w;
            acc[2][4] += a2 * e1.x; acc[2][5] += a2 * e1.y; acc[2][6] += a2 * e1.z; acc[2][7] += a2 * e1.w;
            acc[2][8] += a2 * e2.x; acc[2][9] += a2 * e2.y;
            acc[3][0] += a3 * e0.x; acc[3][1] += a3 * e0.y; acc[3][2] += a3 * e0.z; acc[3][3] += a3 * e0.w;
            acc[3][4] += a3 * e1.x; acc[3][5] += a3 * e1.y; acc[3][6] += a3 * e1.z; acc[3][7] += a3 * e1.w;
            acc[3][8] += a3 * e2.x; acc[3][9] += a3 * e2.y;
        }
    }

    // wave butterfly: lanes sharing m (l = m mod 4) reduce across 16 substreams
#pragma unroll
    for (int mask = 4; mask <= 32; mask <<= 1)
#pragma unroll
        for (int rr = 0; rr < 4; ++rr)
#pragma unroll
            for (int e = 0; e < E; ++e)
                acc[rr][e] += __shfl_xor(acc[rr][e], mask, 64);

    int w = tid >> 6, l = tid & 63;
    if (l < 4) {
#pragma unroll
        for (int rr = 0; rr < 4; ++rr)
#pragma unroll
            for (int e = 0; e < E; ++e) vredW[w][l][rr * E + e] = acc[rr][e];
    }
    __syncthreads();

    float contrib = 0.f;
    if (tid < TR * E) {
        int row = tid / E, f = tid % E;
        int mm = row & 3, rr = row >> 2;
        float d = 0.f;
#pragma unroll
        for (int e = 0; e < E; ++e) {
            float v = vredW[0][mm][rr * E + e] + vredW[1][mm][rr * E + e]
                    + vredW[2][mm][rr * E + e] + vredW[3][mm][rr * E + e];
            d += v * WpS[f * E + e];
        }
        size_t gi = (size_t)(b * N + i0 + row);
        float r = fmaxf(basePad[gi * LDE + f] + d, 0.f);
        if (FINAL) {
            eout[gi * E + f] = r;          // compact layout into d_out
            float ga = 0.f;
#pragma unroll
            for (int k = 0; k < E; ++k) ga += w_reduc[k] * w_all[k * E + f];
            contrib = r * ga;
        } else {
            eout[gi * LDE + f] = r;        // padded layout in workspace
        }
    }
    if (FINAL) {
#pragma unroll
        for (int off = 32; off >= 1; off >>= 1)
            contrib += __shfl_down(contrib, off, 64);
        if (l == 0) wred[w] = contrib;
        __syncthreads();
        if (tid == 0) atomicAdd(&qsum[b], wred[0] + wred[1] + wred[2] + wred[3]);
    }
}

// ---------------------------------------------------------------------------
// K3: q_vals. q[b,n] = qsum[b] + dot(emb[b,n,:], g_act). 64 blocks x 128.
// ---------------------------------------------------------------------------
__global__ __launch_bounds__(128) void k_q(const float* __restrict__ emb,
                                           const float* __restrict__ w_reduc,
                                           const float* __restrict__ w_act,
                                           const float* __restrict__ qsum,
                                           float* __restrict__ qv) {
    int bx = blockIdx.x;
    int b = bx >> 3;
    int row = ((bx & 7) << 7) + threadIdx.x;
    float g_act[E];
#pragma unroll
    for (int e = 0; e < E; ++e) {
        float ss = 0.f;
#pragma unroll
        for (int k = 0; k < E; ++k) ss += w_reduc[E + k] * w_act[k * E + e];
        g_act[e] = ss;
    }
    const float* er = emb + ((size_t)(b << 10) + row) * E;
    float d = 0.f;
#pragma unroll
    for (int e = 0; e < 5; ++e) {
        float2 v = *(const float2*)(er + 2 * e);
        d += v.x * g_act[2 * e] + v.y * g_act[2 * e + 1];
    }
    qv[(b << 10) + row] = qsum[b] + d;
}

extern "C" void kernel_launch(void* const* d_in, const int* in_sizes, int n_in,
                              void* d_out, int out_size, void* d_ws, size_t ws_size,
                              hipStream_t stream) {
    const float* features  = (const float*)d_in[0];
    const float* weights   = (const float*)d_in[1];
    const float* adjacency = (const float*)d_in[2];
    const float* w_sel     = (const float*)d_in[3];
    const float* w_pri     = (const float*)d_in[4];
    const float* w_nbw     = (const float*)d_in[5];
    const float* w_ew      = (const float*)d_in[6];
    const float* w_reduc   = (const float*)d_in[7];
    const float* w_all     = (const float*)d_in[8];
    const float* w_act     = (const float*)d_in[9];

    float* out     = (float*)d_out;
    float* qv      = out;              // B*N
    float* emb_out = out + B * N;      // B*N*E

    float* ws      = (float*)d_ws;
    float* basePad = ws;                               // B*N*LDE = 163840
    float* eA      = basePad + (size_t)B * N * LDE;    // 163840
    float* eB      = eA + (size_t)B * N * LDE;         // 163840
    float* qsum    = eB + (size_t)B * N * LDE;         // 8

    k_base<<<256, 256, 0, stream>>>(weights, features, w_sel, w_nbw, w_ew,
                                    basePad, eA, qsum);
    // ref iter 1 (emb=0) == relu(base) == eA; 4 remaining iterations:
    k_iter<0><<<512, 256, 0, stream>>>(adjacency, eA, basePad, w_pri,
                                       w_reduc, w_all, eB, qsum);
    k_iter<0><<<512, 256, 0, stream>>>(adjacency, eB, basePad, w_pri,
                                       w_reduc, w_all, eA, qsum);
    k_iter<0><<<512, 256, 0, stream>>>(adjacency, eA, basePad, w_pri,
                                       w_reduc, w_all, eB, qsum);
    k_iter<1><<<512, 256, 0, stream>>>(adjacency, eB, basePad, w_pri,
                                       w_reduc, w_all, emb_out, qsum);
    k_q<<<64, 128, 0, stream>>>(emb_out, w_reduc, w_act, qsum, qv);
}